// Round 1
// baseline (590.231 us; speedup 1.0000x reference)
//
#include <hip/hip_runtime.h>
#include <hip/hip_bf16.h>

#define DIM 64
#define SCALE 0.125f

// ---------------- CSR build ----------------

__global__ void k_hist(const int* __restrict__ recv, int* __restrict__ deg, int E) {
    int e = blockIdx.x * blockDim.x + threadIdx.x;
    if (e < E) atomicAdd(&deg[recv[e]], 1);
}

__global__ __launch_bounds__(1024) void k_scan1(const int* __restrict__ deg,
                                                int* __restrict__ incl,
                                                int* __restrict__ bsums, int N) {
    __shared__ int sm[1024];
    int t = threadIdx.x;
    int i = blockIdx.x * 1024 + t;
    int v = (i < N) ? deg[i] : 0;
    sm[t] = v;
    __syncthreads();
    for (int off = 1; off < 1024; off <<= 1) {
        int add = (t >= off) ? sm[t - off] : 0;
        __syncthreads();
        sm[t] += add;
        __syncthreads();
    }
    if (i < N) incl[i] = sm[t];
    if (t == 1023) bsums[blockIdx.x] = sm[1023];
}

__global__ void k_scan2(int* __restrict__ bsums, int NB) {
    if (threadIdx.x == 0 && blockIdx.x == 0) {
        int ex = 0;
        for (int b = 0; b < NB; b++) { int t = bsums[b]; bsums[b] = ex; ex += t; }
    }
}

// offs holds per-block inclusive scan on entry; converted to global exclusive in-place.
__global__ void k_scan3(const int* __restrict__ deg, const int* __restrict__ bsums,
                        int* __restrict__ offs, int* __restrict__ cursor, int N, int E) {
    int i = blockIdx.x * blockDim.x + threadIdx.x;
    if (i < N) {
        int ex = offs[i] - deg[i] + bsums[i >> 10];
        offs[i] = ex;
        cursor[i] = ex;
    }
    if (i == 0) offs[N] = E;
}

__global__ void k_scatter(const int* __restrict__ send, const int* __restrict__ recv,
                          int* __restrict__ cursor, int* __restrict__ csr, int E) {
    int e = blockIdx.x * blockDim.x + threadIdx.x;
    if (e < E) {
        int pos = atomicAdd(&cursor[recv[e]], 1);
        csr[pos] = send[e];
    }
}

// ---------------- fused QKV GEMM ----------------
// block = 192 threads (3 waves); wave m computes W_m (0:Q, 1:K, 2:V).
// Lane j holds column j of W_m in 64 VGPRs. x rows staged in LDS; the
// x-value reads are wave-uniform -> broadcast ds_read_b128 (no bank conflicts).
// K,V written interleaved (KV[row][0:64]=K, [64:128]=V) for gather locality.
__global__ __launch_bounds__(192) void k_qkv(const float* __restrict__ x,
                                             const float* __restrict__ Wq,
                                             const float* __restrict__ Wk,
                                             const float* __restrict__ Wv,
                                             float* __restrict__ Q,
                                             float* __restrict__ KV, int N) {
    __shared__ __align__(16) float xs[64 * 64];  // 16 KiB: 64-row chunk
    int tid = threadIdx.x;
    int wv = tid >> 6;
    int j = tid & 63;
    const float* W = (wv == 0) ? Wq : ((wv == 1) ? Wk : Wv);
    float wreg[64];
#pragma unroll
    for (int k = 0; k < 64; k++) wreg[k] = W[k * 64 + j];

    int base = blockIdx.x * 64;  // first row of this chunk
    // cooperative staging: 64 rows * 16 float4
    for (int idx = tid; idx < 1024; idx += 192) {
        int g = base * 16 + idx;
        float4 val = make_float4(0.f, 0.f, 0.f, 0.f);
        if (g < N * 16) val = ((const float4*)x)[g];
        ((float4*)xs)[idx] = val;
    }
    __syncthreads();

    int rmax = min(64, N - base);
    for (int r0 = 0; r0 < rmax; r0 += 4) {
        float acc[4] = {0.f, 0.f, 0.f, 0.f};
#pragma unroll
        for (int k4 = 0; k4 < 16; k4++) {
#pragma unroll
            for (int i = 0; i < 4; i++) {
                float4 xv = ((const float4*)xs)[(r0 + i) * 16 + k4];
                acc[i] = fmaf(xv.x, wreg[k4 * 4 + 0], acc[i]);
                acc[i] = fmaf(xv.y, wreg[k4 * 4 + 1], acc[i]);
                acc[i] = fmaf(xv.z, wreg[k4 * 4 + 2], acc[i]);
                acc[i] = fmaf(xv.w, wreg[k4 * 4 + 3], acc[i]);
            }
        }
#pragma unroll
        for (int i = 0; i < 4; i++) {
            int row = base + r0 + i;
            if (row < N) {
                if (wv == 0) Q[row * 64 + j] = acc[i];
                else         KV[row * 128 + (wv - 1) * 64 + j] = acc[i];
            }
        }
    }
}

// ---------------- attention + fused output GEMM ----------------
// One wave per receiver node. Lane = (group g = lane>>4, sublane = lane&15).
// Each group handles one edge; sublane covers 4 dims via float4 => 4 edges
// in flight per wave, dot reduced with 4 shfl_xor steps (masks 1,2,4,8),
// group partials combined with masks 16,32. Max-free softmax (logits are
// O(1); exp cannot overflow fp32 here; softmax is shift-invariant anyway).
// Epilogue: res = x[r] + o @ Wo with Wo columns in registers, o broadcast
// from wave-private LDS (explicit lgkmcnt wait; no block-wide sync needed).
__global__ __launch_bounds__(256) void k_attn(const float* __restrict__ Q,
                                              const float* __restrict__ KV,
                                              const float* __restrict__ x,
                                              const float* __restrict__ Wo,
                                              const int* __restrict__ offs,
                                              const int* __restrict__ csr,
                                              float* __restrict__ out, int N) {
    __shared__ __align__(16) float osh[4][64];
    int tid = threadIdx.x;
    int wv = tid >> 6;
    int lane = tid & 63;
    int g = lane >> 4;
    int sub = lane & 15;

    float wo[64];
#pragma unroll
    for (int k = 0; k < 64; k++) wo[k] = Wo[k * 64 + lane];

    int wave_id = blockIdx.x * 4 + wv;
    int nwaves = gridDim.x * 4;

    for (int r = wave_id; r < N; r += nwaves) {
        int start = offs[r];
        int end = offs[r + 1];
        float4 q4 = ((const float4*)Q)[r * 16 + sub];
        float4 acc = make_float4(0.f, 0.f, 0.f, 0.f);
        float dpart = 0.f;

        for (int b = start; b < end; b += 4) {
            int e = b + g;
            bool valid = e < end;
            int s = valid ? csr[e] : 0;
            float4 k4 = ((const float4*)KV)[s * 32 + sub];
            float dot = q4.x * k4.x + q4.y * k4.y + q4.z * k4.z + q4.w * k4.w;
            dot += __shfl_xor(dot, 1);
            dot += __shfl_xor(dot, 2);
            dot += __shfl_xor(dot, 4);
            dot += __shfl_xor(dot, 8);
            float w = valid ? __expf(dot * SCALE) : 0.f;
            float4 v4 = ((const float4*)KV)[s * 32 + 16 + sub];
            acc.x = fmaf(w, v4.x, acc.x);
            acc.y = fmaf(w, v4.y, acc.y);
            acc.z = fmaf(w, v4.z, acc.z);
            acc.w = fmaf(w, v4.w, acc.w);
            dpart += w;
        }
        // combine the 4 groups' partials
        dpart += __shfl_xor(dpart, 16); dpart += __shfl_xor(dpart, 32);
        acc.x += __shfl_xor(acc.x, 16); acc.x += __shfl_xor(acc.x, 32);
        acc.y += __shfl_xor(acc.y, 16); acc.y += __shfl_xor(acc.y, 32);
        acc.z += __shfl_xor(acc.z, 16); acc.z += __shfl_xor(acc.z, 32);
        acc.w += __shfl_xor(acc.w, 16); acc.w += __shfl_xor(acc.w, 32);

        float inv = (dpart > 0.f) ? (1.0f / dpart) : 0.f;
        float4 o4 = make_float4(acc.x * inv, acc.y * inv, acc.z * inv, acc.w * inv);

        if (g == 0) *((float4*)&osh[wv][sub * 4]) = o4;
        asm volatile("s_waitcnt lgkmcnt(0)" ::: "memory");

        float res = x[r * 64 + lane];
#pragma unroll
        for (int d4 = 0; d4 < 16; d4++) {
            float4 ov = *((const float4*)&osh[wv][d4 * 4]);
            res = fmaf(ov.x, wo[d4 * 4 + 0], res);
            res = fmaf(ov.y, wo[d4 * 4 + 1], res);
            res = fmaf(ov.z, wo[d4 * 4 + 2], res);
            res = fmaf(ov.w, wo[d4 * 4 + 3], res);
        }
        out[r * 64 + lane] = res;
        asm volatile("s_waitcnt lgkmcnt(0)" ::: "memory");  // reads done before next node's osh write
    }
}

// ---------------- launch ----------------

extern "C" void kernel_launch(void* const* d_in, const int* in_sizes, int n_in,
                              void* d_out, int out_size, void* d_ws, size_t ws_size,
                              hipStream_t stream) {
    const float* x  = (const float*)d_in[0];
    const int* edge = (const int*)d_in[1];
    const float* Wq = (const float*)d_in[2];
    const float* Wk = (const float*)d_in[3];
    const float* Wv = (const float*)d_in[4];
    const float* Wo = (const float*)d_in[5];
    float* out = (float*)d_out;

    int N = in_sizes[0] / DIM;
    int E = in_sizes[1] / 2;

    // workspace carve (256B aligned). Total ~84.5 MB for N=100K, E=1.6M.
    char* p = (char*)d_ws;
    auto carve = [&](size_t bytes) {
        char* r = p;
        p += ((bytes + 255) / 256) * 256;
        return r;
    };
    float* Q      = (float*)carve((size_t)N * 64 * 4);
    float* KV     = (float*)carve((size_t)N * 128 * 4);
    int*   deg    = (int*)carve((size_t)N * 4);
    int*   offs   = (int*)carve((size_t)(N + 1) * 4);
    int*   cursor = (int*)carve((size_t)N * 4);
    int*   bsums  = (int*)carve(4096);
    int*   csr    = (int*)carve((size_t)E * 4);
    (void)ws_size; (void)n_in; (void)out_size;

    const int* send = edge;
    const int* recv = edge + E;

    hipMemsetAsync(deg, 0, (size_t)N * 4, stream);
    k_hist<<<(E + 255) / 256, 256, 0, stream>>>(recv, deg, E);
    int NB = (N + 1023) / 1024;
    k_scan1<<<NB, 1024, 0, stream>>>(deg, offs, bsums, N);
    k_scan2<<<1, 64, 0, stream>>>(bsums, NB);
    k_scan3<<<(N + 255) / 256, 256, 0, stream>>>(deg, bsums, offs, cursor, N, E);
    k_scatter<<<(E + 255) / 256, 256, 0, stream>>>(send, recv, cursor, csr, E);
    k_qkv<<<(N + 63) / 64, 192, 0, stream>>>(x, Wq, Wk, Wv, Q, KV, N);
    k_attn<<<2048, 256, 0, stream>>>(Q, KV, x, Wo, offs, csr, out, N);
}